// Round 1
// baseline (251.909 us; speedup 1.0000x reference)
//
#include <hip/hip_runtime.h>

#define OUT_W 1024
#define OUT_H 1024

// One block per (b,n) box. 256 threads; each thread produces one float4 of
// vector_x and one float4 of vector_y (1024 elements per row).
// All per-box parameters are wave-uniform (derived from blockIdx.x) so the
// compiler scalarizes the loads + sigma chain; the per-lane work is just
// p - center, one v_exp_f32, and a cndmask.
__global__ __launch_bounds__(256)
void gv_kernel(const float* __restrict__ center,
               const float* __restrict__ wh,
               float* __restrict__ out_x,
               float* __restrict__ out_y)
{
    const int bn = blockIdx.x;
    const int t  = threadIdx.x;

    const float cx = center[2 * bn + 0];
    const float cy = center[2 * bn + 1];
    const float Wb = wh[2 * bn + 0];
    const float Hb = wh[2 * bn + 1];

    // kernel size = floor(W/2)*2 - 1 ; radius = floor((ks-1)/2) ; sigma = floor(r/3)
    // all in fp32 exactly like the jnp reference
    const float ksw = floorf(Wb * 0.5f) * 2.0f - 1.0f;
    const float rw  = floorf((ksw - 1.0f) * 0.5f);
    const float sw  = floorf(rw / 3.0f);
    const float ksh = floorf(Hb * 0.5f) * 2.0f - 1.0f;
    const float rh  = floorf((ksh - 1.0f) * 0.5f);
    const float sh  = floorf(rh / 3.0f);

    const bool zero_box = ((cx + cy) + (Wb + Hb)) == 0.0f;

    // SCALE = upscale/stride = 1.0 ; trunc toward zero as the astype(int32)
    const float x = truncf(cx);
    const float y = truncf(cy);

    const float ul0 = x - rw;
    const float ul1 = y - rh;
    const float br0 = x + rw + 1.0f;
    const float br1 = y + rh + 1.0f;

    // is_point_in_img: inclusive upper bound
    const bool in_ul = (ul0 >= 0.0f) && (ul0 <= (float)OUT_W) &&
                       (ul1 >= 0.0f) && (ul1 <= (float)OUT_H);
    const bool in_br = (br0 >= 0.0f) && (br0 <= (float)OUT_W) &&
                       (br1 >= 0.0f) && (br1 <= (float)OUT_H);
    const bool active = (!zero_box) && (sw != 0.0f) && (sh != 0.0f) && (in_ul || in_br);

    // safe sigma (reference guards sig==0 inside exp even though mask kills it)
    const float ssw = (sw == 0.0f) ? 1.0f : sw;
    const float ssh = (sh == 0.0f) ? 1.0f : sh;
    const float iw  = -1.0f / (2.0f * ssw * ssw);
    const float ih  = -1.0f / (2.0f * ssh * ssh);

    float rx[4], ry[4];
    const int p0 = t * 4;
#pragma unroll
    for (int i = 0; i < 4; ++i) {
        const float p  = (float)(p0 + i);
        const float dx = p - x;
        const float dy = p - y;
        const bool mx = active && (p >= ul0) && (p < br0);
        const bool my = active && (p >= ul1) && (p < br1);
        rx[i] = mx ? __expf(dx * dx * iw) : 0.0f;
        ry[i] = my ? __expf(dy * dy * ih) : 0.0f;
    }

    const size_t row = (size_t)bn * (OUT_W / 4) + t;
    reinterpret_cast<float4*>(out_x)[row] = make_float4(rx[0], rx[1], rx[2], rx[3]);
    reinterpret_cast<float4*>(out_y)[row] = make_float4(ry[0], ry[1], ry[2], ry[3]);
}

extern "C" void kernel_launch(void* const* d_in, const int* in_sizes, int n_in,
                              void* d_out, int out_size, void* d_ws, size_t ws_size,
                              hipStream_t stream) {
    const float* center = (const float*)d_in[0];  // [B,N,2]
    const float* wh     = (const float*)d_in[1];  // [B,N,2]
    float* out = (float*)d_out;                   // vector_x ++ vector_y, fp32

    const int BN = in_sizes[0] / 2;               // B*N = 32768
    float* out_x = out;
    float* out_y = out + (size_t)BN * OUT_W;

    gv_kernel<<<dim3(BN), dim3(256), 0, stream>>>(center, wh, out_x, out_y);
}